// Round 2
// baseline (289.025 us; speedup 1.0000x reference)
//
#include <hip/hip_runtime.h>
#include <math.h>

#define B_   2
#define S_   2048
#define H_   1024
#define NH_  16
#define NKV_ 4
#define HD_  64
#define R_   (NH_ / NKV_)   // 4 q-heads per kv-head
#define QKVW 1536           // qkv row width (q 0..1023 | k 1024..1279 | v 1280..1535)

typedef __attribute__((ext_vector_type(8))) short bf16x8;
typedef __attribute__((ext_vector_type(4))) float f32x4;

__device__ inline short f2bf(float f) {
    unsigned u = __float_as_uint(f);
    u += 0x7FFF + ((u >> 16) & 1);     // RNE to bf16
    return (short)(u >> 16);
}

// async global->LDS, 16 B per lane; lptr is the wave-uniform chunk base,
// HW scatters lane i's 16 B at lptr + i*16 (m97/m104 semantics).
__device__ inline void gload_lds16(const void* gptr, void* lptr) {
    __builtin_amdgcn_global_load_lds(
        (const __attribute__((address_space(1))) unsigned int*)gptr,
        (__attribute__((address_space(3))) unsigned int*)lptr,
        16, 0, 0);
}

// ---------------------------------------------------------------------------
// All four weight transposes in one launch. 640 blocks of 64x64 tiles:
// [0,256) Wq -> Wqkvt rows 0..1023 ; [256,320) Wk -> rows 1024..1279 ;
// [320,384) Wv -> rows 1280..1535 ; [384,640) Wo -> Wot.
// ---------------------------------------------------------------------------
__global__ __launch_bounds__(256) void tconv_all(const float* __restrict__ Wq,
                                                 const float* __restrict__ Wk,
                                                 const float* __restrict__ Wv,
                                                 const float* __restrict__ Wo,
                                                 short* __restrict__ Wqkvt,
                                                 short* __restrict__ Wot) {
    __shared__ short T[64][68];
    const int bx = blockIdx.x;
    const float* W; short* Wt; int N, idx;
    if (bx < 256)      { W = Wq; Wt = Wqkvt;                     N = 1024; idx = bx; }
    else if (bx < 320) { W = Wk; Wt = Wqkvt + 1024 * 1024;       N = 256;  idx = bx - 256; }
    else if (bx < 384) { W = Wv; Wt = Wqkvt + 1280 * 1024;       N = 256;  idx = bx - 320; }
    else               { W = Wo; Wt = Wot;                       N = 1024; idx = bx - 384; }
    const int ntiles = N >> 6;
    const int n0 = (idx % ntiles) * 64;
    const int k0 = (idx / ntiles) * 64;

    const int tid = threadIdx.x;
    const int r  = tid >> 4;
    const int c4 = (tid & 15) * 4;
#pragma unroll
    for (int t = 0; t < 4; t++) {
        int row = t * 16 + r;
        float4 v = *(const float4*)&W[(size_t)(k0 + row) * N + n0 + c4];
        T[c4 + 0][row] = f2bf(v.x);
        T[c4 + 1][row] = f2bf(v.y);
        T[c4 + 2][row] = f2bf(v.z);
        T[c4 + 3][row] = f2bf(v.w);
    }
    __syncthreads();
#pragma unroll
    for (int t = 0; t < 4; t++) {
        int row = t * 16 + r;          // n index
        short4 o = *(short4*)&T[row][c4];
        *(short4*)&Wt[(size_t)(n0 + row) * 1024 + k0 + c4] = o;
    }
}

// ---------------------------------------------------------------------------
// Fused GEMM1: qkv = bf16(x) @ Wqkvt^T with
//   - A staged from fp32 x via registers (convert_x fused),
//   - RoPE applied in the fp32 epilogue for q/k cols,
//   - v cols written TRANSPOSED into Vtg.
// 64x128 tile, BK=32, 256 threads = 4 waves.
// ---------------------------------------------------------------------------
__global__ __launch_bounds__(256) void gemm1_fused(const float* __restrict__ x,
                                                   const short* __restrict__ Bt,
                                                   short* __restrict__ qkv,
                                                   short* __restrict__ Vtg,
                                                   const float* __restrict__ cosb,
                                                   const float* __restrict__ sinb) {
    __shared__ short Ah[64 * 32];    // [row][k] 4 KB
    __shared__ short Bh[128 * 32];   // [col][k] 8 KB

    const int tid  = threadIdx.x;
    const int w    = tid >> 6;
    const int lane = tid & 63;
    const int ln   = lane & 15;
    const int qd   = lane >> 4;
    const int wr   = w >> 1, wc = w & 1;
    const int row0 = blockIdx.y * 64;
    const int col0 = blockIdx.x * 128;

    const int sr = lane >> 2;        // 0..15
    const int sk = (lane & 3) * 8;   // k element offset
    const int ar  = tid >> 2;        // 0..63  (A convert-stage row)
    const int ac8 = (tid & 3) * 8;   // 0,8,16,24

    f32x4 acc[2][4];
#pragma unroll
    for (int mi = 0; mi < 2; mi++)
#pragma unroll
        for (int ni = 0; ni < 4; ni++)
            acc[mi][ni] = (f32x4){0.f, 0.f, 0.f, 0.f};

    for (int k0 = 0; k0 < 1024; k0 += 32) {
        __syncthreads();   // previous iter's frag reads done
        // A: fp32 -> bf16 in registers -> LDS
        {
            const float* xp = x + (size_t)(row0 + ar) * H_ + k0 + ac8;
            float4 a = *(const float4*)xp;
            float4 b2 = *(const float4*)(xp + 4);
            bf16x8 o;
            o[0] = f2bf(a.x);  o[1] = f2bf(a.y);  o[2] = f2bf(a.z);  o[3] = f2bf(a.w);
            o[4] = f2bf(b2.x); o[5] = f2bf(b2.y); o[6] = f2bf(b2.z); o[7] = f2bf(b2.w);
            *(bf16x8*)&Ah[ar * 32 + ac8] = o;
        }
        // B: bf16 glds (wave w stages cols w*32..w*32+31)
        gload_lds16(Bt + (size_t)(col0 + w * 32 + sr) * 1024 + k0 + sk, &Bh[(w * 32) * 32]);
        gload_lds16(Bt + (size_t)(col0 + w * 32 + 16 + sr) * 1024 + k0 + sk, &Bh[(w * 32 + 16) * 32]);
        __syncthreads();

        bf16x8 af[2], bfr[4];
#pragma unroll
        for (int mi = 0; mi < 2; mi++)
            af[mi] = *(const bf16x8*)&Ah[(wr * 32 + mi * 16 + ln) * 32 + qd * 8];
#pragma unroll
        for (int ni = 0; ni < 4; ni++)
            bfr[ni] = *(const bf16x8*)&Bh[(wc * 64 + ni * 16 + ln) * 32 + qd * 8];
#pragma unroll
        for (int mi = 0; mi < 2; mi++)
#pragma unroll
            for (int ni = 0; ni < 4; ni++)
                acc[mi][ni] = __builtin_amdgcn_mfma_f32_16x16x32_bf16(af[mi], bfr[ni], acc[mi][ni], 0, 0, 0);
    }

    const int colw = col0 + wc * 64;          // this wave's 64-col half
    if (colw < H_ + NKV_ * HD_) {
        // ---- q or k columns: RoPE in fp32, store bf16 to qkv ----
#pragma unroll
        for (int mi = 0; mi < 2; mi++)
#pragma unroll
            for (int i = 0; i < 4; i++) {
                const int row  = row0 + wr * 32 + mi * 16 + qd * 4 + i;
                const int spos = row & (S_ - 1);
                const float* cp = cosb + (size_t)spos * HD_;
                const float* sp = sinb + (size_t)spos * HD_;
                float o0[4];
#pragma unroll
                for (int ni = 0; ni < 2; ni++) {
                    const int d = ni * 16 + ln;
                    float x0 = acc[mi][ni][i], x1 = acc[mi][ni + 2][i];
                    o0[ni]     = x0 * cp[d]      - x1 * sp[d];
                    o0[ni + 2] = x1 * cp[d + 32] + x0 * sp[d + 32];
                }
                short* Cp = qkv + (size_t)row * QKVW + colw + ln;
#pragma unroll
                for (int ni = 0; ni < 4; ni++) Cp[ni * 16] = f2bf(o0[ni]);
            }
    } else {
        // ---- v columns: transposed scatter into Vtg[(b*NKV+g)*HD+d][s] ----
        const int g = (colw - (H_ + NKV_ * HD_)) >> 6;
#pragma unroll
        for (int mi = 0; mi < 2; mi++) {
            const int rbase = row0 + wr * 32 + mi * 16 + qd * 4;   // i = +0..3
            const int bg = ((rbase >> 11) * NKV_) + g;
            const int s0 = rbase & (S_ - 1);
#pragma unroll
            for (int ni = 0; ni < 4; ni++) {
                const int d = ni * 16 + ln;
                short4 pk = { f2bf(acc[mi][ni][0]), f2bf(acc[mi][ni][1]),
                              f2bf(acc[mi][ni][2]), f2bf(acc[mi][ni][3]) };
                *(short4*)&Vtg[((size_t)bg * HD_ + d) * S_ + s0] = pk;
            }
        }
    }
}

// ---------------------------------------------------------------------------
// bf16 MFMA GEMM, B^T form: C[M,N] = A[M,K] @ Bt[N,K]^T (fp32 out).
// 64x128 tile, BK=32, 256 threads. Used for the output projection.
// ---------------------------------------------------------------------------
__global__ __launch_bounds__(256) void gemm2_bt(const short* __restrict__ A, int lda,
                                                const short* __restrict__ Bt,
                                                float* __restrict__ C, int ldc,
                                                int K) {
    __shared__ short Ah[64 * 32];
    __shared__ short Bh[128 * 32];

    const int tid  = threadIdx.x;
    const int w    = tid >> 6;
    const int lane = tid & 63;
    const int ln   = lane & 15;
    const int qd   = lane >> 4;
    const int wr   = w >> 1, wc = w & 1;
    const int row0 = blockIdx.y * 64;
    const int col0 = blockIdx.x * 128;

    const int sr = lane >> 2;
    const int sk = (lane & 3) * 8;

    f32x4 acc[2][4];
#pragma unroll
    for (int mi = 0; mi < 2; mi++)
#pragma unroll
        for (int ni = 0; ni < 4; ni++)
            acc[mi][ni] = (f32x4){0.f, 0.f, 0.f, 0.f};

    for (int k0 = 0; k0 < K; k0 += 32) {
        __syncthreads();
        gload_lds16(A + (size_t)(row0 + w * 16 + sr) * lda + k0 + sk, &Ah[(w * 16) * 32]);
        gload_lds16(Bt + (size_t)(col0 + w * 32 + sr) * K + k0 + sk, &Bh[(w * 32) * 32]);
        gload_lds16(Bt + (size_t)(col0 + w * 32 + 16 + sr) * K + k0 + sk, &Bh[(w * 32 + 16) * 32]);
        __syncthreads();

        bf16x8 af[2], bfr[4];
#pragma unroll
        for (int mi = 0; mi < 2; mi++)
            af[mi] = *(const bf16x8*)&Ah[(wr * 32 + mi * 16 + ln) * 32 + qd * 8];
#pragma unroll
        for (int ni = 0; ni < 4; ni++)
            bfr[ni] = *(const bf16x8*)&Bh[(wc * 64 + ni * 16 + ln) * 32 + qd * 8];
#pragma unroll
        for (int mi = 0; mi < 2; mi++)
#pragma unroll
            for (int ni = 0; ni < 4; ni++)
                acc[mi][ni] = __builtin_amdgcn_mfma_f32_16x16x32_bf16(af[mi], bfr[ni], acc[mi][ni], 0, 0, 0);
    }

#pragma unroll
    for (int mi = 0; mi < 2; mi++)
#pragma unroll
        for (int i = 0; i < 4; i++) {
            const size_t row = row0 + wr * 32 + mi * 16 + qd * 4 + i;
            float* Cp = C + row * ldc + col0 + wc * 64 + ln;
#pragma unroll
            for (int ni = 0; ni < 4; ni++) Cp[ni * 16] = acc[mi][ni][i];
        }
}

// ---------------------------------------------------------------------------
// bf16 MFMA flash attention v13: 16-row waves + register-prefetch pipeline.
//   - 2048 waves (512 blocks x 4) = 2 waves/SIMD (v12 had 1/SIMD: all
//     latency exposed). Wave = 16 q-rows; pair (j, 127-j) = exactly 33
//     k-tiles for every j -> perfectly uniform.
//   - K/V MFMA fragments double-buffered in REGISTERS: tile kt+1's 16
//     global loads issue before tile kt's compute -> L2 latency hides
//     under QK/softmax/PV (counted-vmcnt pattern, compiler-scheduled).
//   - No barriers, no K/V LDS; only per-wave Ps round-trip (2.25 KB/wave).
//   - fid&7 = (b,g): one 512 KB K/V slice per XCD L2.
//   - Causal cndmask only on the diagonal (= last) tile; defer-max THR=8.
// ---------------------------------------------------------------------------
__global__ __launch_bounds__(256, 2) void attn_kernel(short* __restrict__ qkv,
                                                      const short* __restrict__ Vtg,
                                                      const float* __restrict__ maskb) {
    const int tid  = threadIdx.x;
    const int w    = tid >> 6;
    const int lane = tid & 63;
    const int ln   = lane & 15;
    const int qd   = lane >> 4;

    // fid = bg + 8*(r + 4*t):  bg -> XCD, r = head-in-group, t = pair-group
    const int fid = blockIdx.x;          // 0..511
    const int bg  = fid & 7;             // b*NKV+g
    const int u   = fid >> 3;            // 0..63
    const int b   = bg >> 2;
    const int g   = bg & 3;
    const int h   = g * R_ + (u & 3);
    const int t   = u >> 2;              // 0..15
    const int j0  = t * 4 + w;           // 0..63  (this wave's pair index)

    __shared__ short Ps[4][16 * 72];     // per-wave P [row 0..15][key], stride 72
    short* const ps = Ps[w];

    const short* const Kb = qkv + (size_t)b * S_ * QKVW + H_ + g * HD_;
    const short* const Vb = Vtg + (size_t)bg * HD_ * S_;
    const float* const mb = maskb + b * S_;

#pragma unroll 1
    for (int ss = 0; ss < 2; ss++) {
        const int j    = ss ? (127 - j0) : j0;   // 16-row strip index
        const int rowb = j * 16;
        const int nt   = (j >> 2) + 1;           // 64-key tiles

        // ---- Q B-frags: rows rowb+ln ----
        bf16x8 qf0, qf1;
        {
            const short* qp = qkv + (size_t)(b * S_ + rowb + ln) * QKVW + h * HD_;
            qf0 = *(const bf16x8*)&qp[qd * 8];
            qf1 = *(const bf16x8*)&qp[32 + qd * 8];
        }

        f32x4 O[4] = {};
        float mrow = -1e30f;
        float lrow = 0.0f;

        // ---- register double-buffers for K/V fragments ----
        bf16x8 kaA0[4], kaA1[4], vbA[2][4];
        bf16x8 kaB0[4], kaB1[4], vbB[2][4];

        auto load_kv = [&](bf16x8 (&ka0)[4], bf16x8 (&ka1)[4], bf16x8 (&vb)[2][4],
                           int base) {
#pragma unroll
            for (int kg = 0; kg < 4; kg++) {
                const short* kp = Kb + (size_t)(base + kg * 16 + ln) * QKVW;
                ka0[kg] = *(const bf16x8*)&kp[qd * 8];
                ka1[kg] = *(const bf16x8*)&kp[32 + qd * 8];
            }
#pragma unroll
            for (int kc2 = 0; kc2 < 2; kc2++)
#pragma unroll
                for (int dt = 0; dt < 4; dt++)
                    vb[kc2][dt] = *(const bf16x8*)
                        &Vb[(size_t)(dt * 16 + ln) * S_ + base + kc2 * 32 + qd * 8];
        };

        auto tile = [&](const bf16x8 (&ka0)[4], const bf16x8 (&ka1)[4],
                        const bf16x8 (&vb)[2][4], int kt) {
            const int base = kt * 64;

            // per-lane mask bias (L1-broadcast)
            float mt[4][4];
#pragma unroll
            for (int kg = 0; kg < 4; kg++) {
                float4 mv = *(const float4*)&mb[base + kg * 16 + qd * 4];
                mt[kg][0] = (1.0f - mv.x) * -1e9f;
                mt[kg][1] = (1.0f - mv.y) * -1e9f;
                mt[kg][2] = (1.0f - mv.z) * -1e9f;
                mt[kg][3] = (1.0f - mv.w) * -1e9f;
            }

            // QK^T swapped: St[kg][i] = S^T[key][qrow=ln]
            f32x4 St[4];
#pragma unroll
            for (int kg = 0; kg < 4; kg++) {
                f32x4 z = {0.f, 0.f, 0.f, 0.f};
                z = __builtin_amdgcn_mfma_f32_16x16x32_bf16(ka0[kg], qf0, z, 0, 0, 0);
                St[kg] = __builtin_amdgcn_mfma_f32_16x16x32_bf16(ka1[kg], qf1, z, 0, 0, 0);
            }

            const bool diag = (kt == nt - 1);
            const int qrow  = rowb + ln;

            float sc[4][4];
#pragma unroll
            for (int kg = 0; kg < 4; kg++) {
                const int keyb = base + kg * 16 + qd * 4;
#pragma unroll
                for (int i = 0; i < 4; i++) {
                    float v = fmaf(St[kg][i], 0.125f, mt[kg][i]);
                    sc[kg][i] = (diag && (keyb + i > qrow)) ? -1e30f : v;
                }
            }
            float mx = sc[0][0];
#pragma unroll
            for (int kg = 0; kg < 4; kg++)
#pragma unroll
                for (int i = 0; i < 4; i++) mx = fmaxf(mx, sc[kg][i]);
            mx = fmaxf(mx, __shfl_xor(mx, 16));
            mx = fmaxf(mx, __shfl_xor(mx, 32));

            // defer-max (T13): rescale only when some row moved > 8
            if (__ballot(mx > mrow + 8.0f)) {
                float nm    = fmaxf(mrow, mx);
                float alpha = __expf(mrow - nm);
                lrow *= alpha;
#pragma unroll
                for (int i = 0; i < 4; i++) {
                    float av = __shfl(alpha, qd * 4 + i);
#pragma unroll
                    for (int dt = 0; dt < 4; dt++) O[dt][i] *= av;
                }
                mrow = nm;
            }
            const float nm = mrow;

            float ls = 0.0f;
            float pr[4][4];
#pragma unroll
            for (int kg = 0; kg < 4; kg++)
#pragma unroll
                for (int i = 0; i < 4; i++) {
                    float p = __expf(sc[kg][i] - nm);
                    pr[kg][i] = p;
                    ls += p;
                }
            ls += __shfl_xor(ls, 16);
            ls += __shfl_xor(ls, 32);
            lrow += ls;

#pragma unroll
            for (int kg = 0; kg < 4; kg++) {
                short4 pk = { f2bf(pr[kg][0]), f2bf(pr[kg][1]),
                              f2bf(pr[kg][2]), f2bf(pr[kg][3]) };
                *(short4*)&ps[ln * 72 + kg * 16 + qd * 4] = pk;
            }

            // PV: O += P @ V
#pragma unroll
            for (int kc2 = 0; kc2 < 2; kc2++) {
                bf16x8 pa = *(const bf16x8*)&ps[ln * 72 + kc2 * 32 + qd * 8];
#pragma unroll
                for (int dt = 0; dt < 4; dt++)
                    O[dt] = __builtin_amdgcn_mfma_f32_16x16x32_bf16(pa, vb[kc2][dt], O[dt], 0, 0, 0);
            }
        };

        // ---- software-pipelined tile loop (A/B named buffers) ----
        load_kv(kaA0, kaA1, vbA, 0);
        int kt = 0;
        while (true) {
            bool pf = (kt + 1 < nt);
            if (pf) load_kv(kaB0, kaB1, vbB, (kt + 1) * 64);
            tile(kaA0, kaA1, vbA, kt);
            kt++;
            if (!pf) break;
            pf = (kt + 1 < nt);
            if (pf) load_kv(kaA0, kaA1, vbA, (kt + 1) * 64);
            tile(kaB0, kaB1, vbB, kt);
            kt++;
            if (!pf) break;
        }

        // ---- finalize: l replicated over qd; write bf16 into q-slice ----
#pragma unroll
        for (int i = 0; i < 4; i++) {
            float li  = __shfl(lrow, qd * 4 + i);
            float inv = 1.0f / li;
            const int row = rowb + qd * 4 + i;
            short* op = qkv + (size_t)(b * S_ + row) * QKVW + h * HD_ + ln;
#pragma unroll
            for (int dt = 0; dt < 4; dt++) op[dt * 16] = f2bf(O[dt][i] * inv);
        }
    }
}

// ---------------------------------------------------------------------------
extern "C" void kernel_launch(void* const* d_in, const int* in_sizes, int n_in,
                              void* d_out, int out_size, void* d_ws, size_t ws_size,
                              hipStream_t stream) {
    const float* x     = (const float*)d_in[0];
    const float* cosb  = (const float*)d_in[1];
    const float* sinb  = (const float*)d_in[2];
    const float* maskb = (const float*)d_in[3];
    const float* Wq    = (const float*)d_in[4];
    const float* Wk    = (const float*)d_in[5];
    const float* Wv    = (const float*)d_in[6];
    const float* Wo    = (const float*)d_in[7];

    const int M = B_ * S_;   // 4096

    // ws: qkv | Wqkvt | Wot | Vtg  (19.9 MB bf16). d_out used only for out.
    short* qkv   = (short*)d_ws;                     // [4096][1536]
    short* Wqkvt = qkv + (size_t)M * QKVW;           // [1536][1024]
    short* Wot   = Wqkvt + (size_t)QKVW * H_;        // [1024][1024]
    short* Vtg   = Wot + (size_t)H_ * H_;            // [8*64][2048]
    float* out   = (float*)d_out;

    dim3 blk(256);

    tconv_all<<<dim3(640), blk, 0, stream>>>(Wq, Wk, Wv, Wo, Wqkvt, Wot);

    // GEMM1 fused: qkv(q,k roped) + Vtg, straight from fp32 x
    gemm1_fused<<<dim3(QKVW / 128, M / 64), blk, 0, stream>>>(x, Wqkvt, qkv, Vtg, cosb, sinb);

    // attention: 512 blocks (8 bg x 4 heads x 16 pair-groups), 33 tiles/wave
    attn_kernel<<<dim3(512), blk, 0, stream>>>(qkv, Vtg, maskb);

    // GEMM2: out = attn_out(q-slice of qkv, lda=1536) @ Wot^T  (fp32 out)
    gemm2_bt<<<dim3(H_ / 128, M / 64), blk, 0, stream>>>(qkv, QKVW, Wot, out, H_, H_);
}

// Round 3
// 282.980 us; speedup vs baseline: 1.0214x; 1.0214x over previous
//
#include <hip/hip_runtime.h>
#include <math.h>

#define B_   2
#define S_   2048
#define H_   1024
#define NH_  16
#define NKV_ 4
#define HD_  64
#define R_   (NH_ / NKV_)   // 4 q-heads per kv-head
#define QKVW 1536           // qkv row width (q 0..1023 | k 1024..1279 | v 1280..1535)

typedef __attribute__((ext_vector_type(8))) short bf16x8;
typedef __attribute__((ext_vector_type(4))) float f32x4;

__device__ inline short f2bf(float f) {
    unsigned u = __float_as_uint(f);
    u += 0x7FFF + ((u >> 16) & 1);     // RNE to bf16
    return (short)(u >> 16);
}

// async global->LDS, 16 B per lane; lptr is the wave-uniform chunk base,
// HW scatters lane i's 16 B at lptr + i*16 (m97/m104 semantics).
__device__ inline void gload_lds16(const void* gptr, void* lptr) {
    __builtin_amdgcn_global_load_lds(
        (const __attribute__((address_space(1))) unsigned int*)gptr,
        (__attribute__((address_space(3))) unsigned int*)lptr,
        16, 0, 0);
}

// ---------------------------------------------------------------------------
// All four weight transposes in one launch. 640 blocks of 64x64 tiles.
// ---------------------------------------------------------------------------
__global__ __launch_bounds__(256) void tconv_all(const float* __restrict__ Wq,
                                                 const float* __restrict__ Wk,
                                                 const float* __restrict__ Wv,
                                                 const float* __restrict__ Wo,
                                                 short* __restrict__ Wqkvt,
                                                 short* __restrict__ Wot) {
    __shared__ short T[64][68];
    const int bx = blockIdx.x;
    const float* W; short* Wt; int N, idx;
    if (bx < 256)      { W = Wq; Wt = Wqkvt;                     N = 1024; idx = bx; }
    else if (bx < 320) { W = Wk; Wt = Wqkvt + 1024 * 1024;       N = 256;  idx = bx - 256; }
    else if (bx < 384) { W = Wv; Wt = Wqkvt + 1280 * 1024;       N = 256;  idx = bx - 320; }
    else               { W = Wo; Wt = Wot;                       N = 1024; idx = bx - 384; }
    const int ntiles = N >> 6;
    const int n0 = (idx % ntiles) * 64;
    const int k0 = (idx / ntiles) * 64;

    const int tid = threadIdx.x;
    const int r  = tid >> 4;
    const int c4 = (tid & 15) * 4;
#pragma unroll
    for (int t = 0; t < 4; t++) {
        int row = t * 16 + r;
        float4 v = *(const float4*)&W[(size_t)(k0 + row) * N + n0 + c4];
        T[c4 + 0][row] = f2bf(v.x);
        T[c4 + 1][row] = f2bf(v.y);
        T[c4 + 2][row] = f2bf(v.z);
        T[c4 + 3][row] = f2bf(v.w);
    }
    __syncthreads();
#pragma unroll
    for (int t = 0; t < 4; t++) {
        int row = t * 16 + r;          // n index
        short4 o = *(short4*)&T[row][c4];
        *(short4*)&Wt[(size_t)(n0 + row) * 1024 + k0 + c4] = o;
    }
}

// ---------------------------------------------------------------------------
// Fused GEMM1: qkv = bf16(x) @ Wqkvt^T  (RoPE epilogue for q/k, V transposed
// scatter into Vtg). 64x128 tile, BK=32, 256 threads = 4 waves.
// ---------------------------------------------------------------------------
__global__ __launch_bounds__(256) void gemm1_fused(const float* __restrict__ x,
                                                   const short* __restrict__ Bt,
                                                   short* __restrict__ qkv,
                                                   short* __restrict__ Vtg,
                                                   const float* __restrict__ cosb,
                                                   const float* __restrict__ sinb) {
    __shared__ short Ah[64 * 32];    // [row][k] 4 KB
    __shared__ short Bh[128 * 32];   // [col][k] 8 KB

    const int tid  = threadIdx.x;
    const int w    = tid >> 6;
    const int lane = tid & 63;
    const int ln   = lane & 15;
    const int qd   = lane >> 4;
    const int wr   = w >> 1, wc = w & 1;
    const int row0 = blockIdx.y * 64;
    const int col0 = blockIdx.x * 128;

    const int sr = lane >> 2;        // 0..15
    const int sk = (lane & 3) * 8;   // k element offset
    const int ar  = tid >> 2;        // 0..63  (A convert-stage row)
    const int ac8 = (tid & 3) * 8;   // 0,8,16,24

    f32x4 acc[2][4];
#pragma unroll
    for (int mi = 0; mi < 2; mi++)
#pragma unroll
        for (int ni = 0; ni < 4; ni++)
            acc[mi][ni] = (f32x4){0.f, 0.f, 0.f, 0.f};

    for (int k0 = 0; k0 < 1024; k0 += 32) {
        __syncthreads();   // previous iter's frag reads done
        // A: fp32 -> bf16 in registers -> LDS
        {
            const float* xp = x + (size_t)(row0 + ar) * H_ + k0 + ac8;
            float4 a = *(const float4*)xp;
            float4 b2 = *(const float4*)(xp + 4);
            bf16x8 o;
            o[0] = f2bf(a.x);  o[1] = f2bf(a.y);  o[2] = f2bf(a.z);  o[3] = f2bf(a.w);
            o[4] = f2bf(b2.x); o[5] = f2bf(b2.y); o[6] = f2bf(b2.z); o[7] = f2bf(b2.w);
            *(bf16x8*)&Ah[ar * 32 + ac8] = o;
        }
        // B: bf16 glds (wave w stages cols w*32..w*32+31)
        gload_lds16(Bt + (size_t)(col0 + w * 32 + sr) * 1024 + k0 + sk, &Bh[(w * 32) * 32]);
        gload_lds16(Bt + (size_t)(col0 + w * 32 + 16 + sr) * 1024 + k0 + sk, &Bh[(w * 32 + 16) * 32]);
        __syncthreads();

        bf16x8 af[2], bfr[4];
#pragma unroll
        for (int mi = 0; mi < 2; mi++)
            af[mi] = *(const bf16x8*)&Ah[(wr * 32 + mi * 16 + ln) * 32 + qd * 8];
#pragma unroll
        for (int ni = 0; ni < 4; ni++)
            bfr[ni] = *(const bf16x8*)&Bh[(wc * 64 + ni * 16 + ln) * 32 + qd * 8];
#pragma unroll
        for (int mi = 0; mi < 2; mi++)
#pragma unroll
            for (int ni = 0; ni < 4; ni++)
                acc[mi][ni] = __builtin_amdgcn_mfma_f32_16x16x32_bf16(af[mi], bfr[ni], acc[mi][ni], 0, 0, 0);
    }

    const int colw = col0 + wc * 64;          // this wave's 64-col half
    if (colw < H_ + NKV_ * HD_) {
        // ---- q or k columns: RoPE in fp32, store bf16 to qkv ----
#pragma unroll
        for (int mi = 0; mi < 2; mi++)
#pragma unroll
            for (int i = 0; i < 4; i++) {
                const int row  = row0 + wr * 32 + mi * 16 + qd * 4 + i;
                const int spos = row & (S_ - 1);
                const float* cp = cosb + (size_t)spos * HD_;
                const float* sp = sinb + (size_t)spos * HD_;
                float o0[4];
#pragma unroll
                for (int ni = 0; ni < 2; ni++) {
                    const int d = ni * 16 + ln;
                    float x0 = acc[mi][ni][i], x1 = acc[mi][ni + 2][i];
                    o0[ni]     = x0 * cp[d]      - x1 * sp[d];
                    o0[ni + 2] = x1 * cp[d + 32] + x0 * sp[d + 32];
                }
                short* Cp = qkv + (size_t)row * QKVW + colw + ln;
#pragma unroll
                for (int ni = 0; ni < 4; ni++) Cp[ni * 16] = f2bf(o0[ni]);
            }
    } else {
        // ---- v columns: transposed scatter into Vtg[(b*NKV+g)*HD+d][s] ----
        const int g = (colw - (H_ + NKV_ * HD_)) >> 6;
#pragma unroll
        for (int mi = 0; mi < 2; mi++) {
            const int rbase = row0 + wr * 32 + mi * 16 + qd * 4;   // i = +0..3
            const int bg = ((rbase >> 11) * NKV_) + g;
            const int s0 = rbase & (S_ - 1);
#pragma unroll
            for (int ni = 0; ni < 4; ni++) {
                const int d = ni * 16 + ln;
                short4 pk = { f2bf(acc[mi][ni][0]), f2bf(acc[mi][ni][1]),
                              f2bf(acc[mi][ni][2]), f2bf(acc[mi][ni][3]) };
                *(short4*)&Vtg[((size_t)bg * HD_ + d) * S_ + s0] = pk;
            }
        }
    }
}

// ---------------------------------------------------------------------------
// bf16 MFMA GEMM, B^T form: C[M,N] = A[M,K] @ Bt[N,K]^T (fp32 out).
// 64x128 tile, BK=32, 256 threads. Used for the output projection.
// ---------------------------------------------------------------------------
__global__ __launch_bounds__(256) void gemm2_bt(const short* __restrict__ A, int lda,
                                                const short* __restrict__ Bt,
                                                float* __restrict__ C, int ldc,
                                                int K) {
    __shared__ short Ah[64 * 32];
    __shared__ short Bh[128 * 32];

    const int tid  = threadIdx.x;
    const int w    = tid >> 6;
    const int lane = tid & 63;
    const int ln   = lane & 15;
    const int qd   = lane >> 4;
    const int wr   = w >> 1, wc = w & 1;
    const int row0 = blockIdx.y * 64;
    const int col0 = blockIdx.x * 128;

    const int sr = lane >> 2;
    const int sk = (lane & 3) * 8;

    f32x4 acc[2][4];
#pragma unroll
    for (int mi = 0; mi < 2; mi++)
#pragma unroll
        for (int ni = 0; ni < 4; ni++)
            acc[mi][ni] = (f32x4){0.f, 0.f, 0.f, 0.f};

    for (int k0 = 0; k0 < K; k0 += 32) {
        __syncthreads();
        gload_lds16(A + (size_t)(row0 + w * 16 + sr) * lda + k0 + sk, &Ah[(w * 16) * 32]);
        gload_lds16(Bt + (size_t)(col0 + w * 32 + sr) * K + k0 + sk, &Bh[(w * 32) * 32]);
        gload_lds16(Bt + (size_t)(col0 + w * 32 + 16 + sr) * K + k0 + sk, &Bh[(w * 32 + 16) * 32]);
        __syncthreads();

        bf16x8 af[2], bfr[4];
#pragma unroll
        for (int mi = 0; mi < 2; mi++)
            af[mi] = *(const bf16x8*)&Ah[(wr * 32 + mi * 16 + ln) * 32 + qd * 8];
#pragma unroll
        for (int ni = 0; ni < 4; ni++)
            bfr[ni] = *(const bf16x8*)&Bh[(wc * 64 + ni * 16 + ln) * 32 + qd * 8];
#pragma unroll
        for (int mi = 0; mi < 2; mi++)
#pragma unroll
            for (int ni = 0; ni < 4; ni++)
                acc[mi][ni] = __builtin_amdgcn_mfma_f32_16x16x32_bf16(af[mi], bfr[ni], acc[mi][ni], 0, 0, 0);
    }

#pragma unroll
    for (int mi = 0; mi < 2; mi++)
#pragma unroll
        for (int i = 0; i < 4; i++) {
            const size_t row = row0 + wr * 32 + mi * 16 + qd * 4 + i;
            float* Cp = C + row * ldc + col0 + wc * 64 + ln;
#pragma unroll
            for (int ni = 0; ni < 4; ni++) Cp[ni * 16] = acc[mi][ni][i];
        }
}

// ---------------------------------------------------------------------------
// bf16 MFMA flash attention v14: 16-row waves, single-buffered tile body.
//   - 2048 waves (512 blocks x 4) = 2 waves/SIMD; TLP (not register
//     double-buffering, which spilled in v13: VGPR cap 128 vs ~220 needed,
//     WRITE_SIZE showed +5 MB scratch) hides K/V L2 latency.
//   - Wave = 16 q-rows; pair (j, 127-j) = exactly 33 k-tiles for every j.
//   - K frags die after QK; V frag loads issue after QK so they overlap
//     the softmax chain -> peak live set ~100 VGPR, fits 128 without spill.
//   - No barriers, no K/V LDS; per-wave Ps round-trip only (2.25 KB/wave).
//   - fid&7 = (b,g): one 512 KB K/V slice per XCD L2.
//   - Causal cndmask only on the diagonal (= last) tile; defer-max THR=8.
// ---------------------------------------------------------------------------
__global__ __launch_bounds__(256, 2) void attn_kernel(short* __restrict__ qkv,
                                                      const short* __restrict__ Vtg,
                                                      const float* __restrict__ maskb) {
    const int tid  = threadIdx.x;
    const int w    = tid >> 6;
    const int lane = tid & 63;
    const int ln   = lane & 15;
    const int qd   = lane >> 4;

    // fid = bg + 8*(r + 4*t):  bg -> XCD, r = head-in-group, t = pair-group
    const int fid = blockIdx.x;          // 0..511
    const int bg  = fid & 7;             // b*NKV+g
    const int u   = fid >> 3;            // 0..63
    const int b   = bg >> 2;
    const int g   = bg & 3;
    const int h   = g * R_ + (u & 3);
    const int t   = u >> 2;              // 0..15
    const int j0  = t * 4 + w;           // 0..63  (this wave's pair index)

    __shared__ short Ps[4][16 * 72];     // per-wave P [row 0..15][key], stride 72
    short* const ps = Ps[w];

    const short* const Kb = qkv + (size_t)b * S_ * QKVW + H_ + g * HD_;
    const short* const Vb = Vtg + (size_t)bg * HD_ * S_;
    const float* const mb = maskb + b * S_;

#pragma unroll 1
    for (int ss = 0; ss < 2; ss++) {
        const int j    = ss ? (127 - j0) : j0;   // 16-row strip index
        const int rowb = j * 16;
        const int nt   = (j >> 2) + 1;           // 64-key tiles

        // ---- Q B-frags: rows rowb+ln ----
        bf16x8 qf0, qf1;
        {
            const short* qp = qkv + (size_t)(b * S_ + rowb + ln) * QKVW + h * HD_;
            qf0 = *(const bf16x8*)&qp[qd * 8];
            qf1 = *(const bf16x8*)&qp[32 + qd * 8];
        }

        f32x4 O[4] = {};
        float mrow = -1e30f;
        float lrow = 0.0f;
        const int qrow = rowb + ln;

#pragma unroll 1
        for (int kt = 0; kt < nt; kt++) {
            const int base = kt * 64;

            // ---- K A-frags from global (L2); dead after QK ----
            bf16x8 ka0[4], ka1[4];
#pragma unroll
            for (int kg = 0; kg < 4; kg++) {
                const short* kp = Kb + (size_t)(base + kg * 16 + ln) * QKVW;
                ka0[kg] = *(const bf16x8*)&kp[qd * 8];
                ka1[kg] = *(const bf16x8*)&kp[32 + qd * 8];
            }

            // ---- QK^T swapped: St[kg][i] = S^T[key][qrow=ln] ----
            f32x4 St[4];
#pragma unroll
            for (int kg = 0; kg < 4; kg++) {
                f32x4 z = {0.f, 0.f, 0.f, 0.f};
                z = __builtin_amdgcn_mfma_f32_16x16x32_bf16(ka0[kg], qf0, z, 0, 0, 0);
                St[kg] = __builtin_amdgcn_mfma_f32_16x16x32_bf16(ka1[kg], qf1, z, 0, 0, 0);
            }

            // ---- V^T B-frags issue now: overlap the softmax chain ----
            bf16x8 vb[2][4];
#pragma unroll
            for (int kc2 = 0; kc2 < 2; kc2++)
#pragma unroll
                for (int dt = 0; dt < 4; dt++)
                    vb[kc2][dt] = *(const bf16x8*)
                        &Vb[(size_t)(dt * 16 + ln) * S_ + base + kc2 * 32 + qd * 8];

            // ---- mask bias + scale + causal (diag tile only) ----
            const bool diag = (kt == nt - 1);
            float sc[4][4];
#pragma unroll
            for (int kg = 0; kg < 4; kg++) {
                const int keyb = base + kg * 16 + qd * 4;
                float4 mv = *(const float4*)&mb[keyb];
                float m0 = (1.0f - mv.x) * -1e9f;
                float m1 = (1.0f - mv.y) * -1e9f;
                float m2 = (1.0f - mv.z) * -1e9f;
                float m3 = (1.0f - mv.w) * -1e9f;
                sc[kg][0] = fmaf(St[kg][0], 0.125f, m0);
                sc[kg][1] = fmaf(St[kg][1], 0.125f, m1);
                sc[kg][2] = fmaf(St[kg][2], 0.125f, m2);
                sc[kg][3] = fmaf(St[kg][3], 0.125f, m3);
                if (diag) {
#pragma unroll
                    for (int i = 0; i < 4; i++)
                        if (keyb + i > qrow) sc[kg][i] = -1e30f;
                }
            }

            float mx = sc[0][0];
#pragma unroll
            for (int kg = 0; kg < 4; kg++)
#pragma unroll
                for (int i = 0; i < 4; i++) mx = fmaxf(mx, sc[kg][i]);
            mx = fmaxf(mx, __shfl_xor(mx, 16));
            mx = fmaxf(mx, __shfl_xor(mx, 32));

            // defer-max (T13): rescale only when some row moved > 8
            if (__ballot(mx > mrow + 8.0f)) {
                float nm    = fmaxf(mrow, mx);
                float alpha = __expf(mrow - nm);
                lrow *= alpha;
#pragma unroll
                for (int i = 0; i < 4; i++) {
                    float av = __shfl(alpha, qd * 4 + i);
#pragma unroll
                    for (int dt = 0; dt < 4; dt++) O[dt][i] *= av;
                }
                mrow = nm;
            }
            const float nm = mrow;

            float ls = 0.0f;
#pragma unroll
            for (int kg = 0; kg < 4; kg++)
#pragma unroll
                for (int i = 0; i < 4; i++) {
                    float p = __expf(sc[kg][i] - nm);
                    sc[kg][i] = p;
                    ls += p;
                }
            ls += __shfl_xor(ls, 16);
            ls += __shfl_xor(ls, 32);
            lrow += ls;

#pragma unroll
            for (int kg = 0; kg < 4; kg++) {
                short4 pk = { f2bf(sc[kg][0]), f2bf(sc[kg][1]),
                              f2bf(sc[kg][2]), f2bf(sc[kg][3]) };
                *(short4*)&ps[ln * 72 + kg * 16 + qd * 4] = pk;
            }

            // ---- PV: O += P @ V ----
#pragma unroll
            for (int kc2 = 0; kc2 < 2; kc2++) {
                bf16x8 pa = *(const bf16x8*)&ps[ln * 72 + kc2 * 32 + qd * 8];
#pragma unroll
                for (int dt = 0; dt < 4; dt++)
                    O[dt] = __builtin_amdgcn_mfma_f32_16x16x32_bf16(pa, vb[kc2][dt], O[dt], 0, 0, 0);
            }
        }

        // ---- finalize: l replicated over qd; write bf16 into q-slice ----
#pragma unroll
        for (int i = 0; i < 4; i++) {
            float li  = __shfl(lrow, qd * 4 + i);
            float inv = 1.0f / li;
            const int row = rowb + qd * 4 + i;
            short* op = qkv + (size_t)(b * S_ + row) * QKVW + h * HD_ + ln;
#pragma unroll
            for (int dt = 0; dt < 4; dt++) op[dt * 16] = f2bf(O[dt][i] * inv);
        }
    }
}

// ---------------------------------------------------------------------------
extern "C" void kernel_launch(void* const* d_in, const int* in_sizes, int n_in,
                              void* d_out, int out_size, void* d_ws, size_t ws_size,
                              hipStream_t stream) {
    const float* x     = (const float*)d_in[0];
    const float* cosb  = (const float*)d_in[1];
    const float* sinb  = (const float*)d_in[2];
    const float* maskb = (const float*)d_in[3];
    const float* Wq    = (const float*)d_in[4];
    const float* Wk    = (const float*)d_in[5];
    const float* Wv    = (const float*)d_in[6];
    const float* Wo    = (const float*)d_in[7];

    const int M = B_ * S_;   // 4096

    // ws: qkv | Wqkvt | Wot | Vtg  (19.9 MB bf16). d_out used only for out.
    short* qkv   = (short*)d_ws;                     // [4096][1536]
    short* Wqkvt = qkv + (size_t)M * QKVW;           // [1536][1024]
    short* Wot   = Wqkvt + (size_t)QKVW * H_;        // [1024][1024]
    short* Vtg   = Wot + (size_t)H_ * H_;            // [8*64][2048]
    float* out   = (float*)d_out;

    dim3 blk(256);

    tconv_all<<<dim3(640), blk, 0, stream>>>(Wq, Wk, Wv, Wo, Wqkvt, Wot);

    // GEMM1 fused: qkv(q,k roped) + Vtg, straight from fp32 x
    gemm1_fused<<<dim3(QKVW / 128, M / 64), blk, 0, stream>>>(x, Wqkvt, qkv, Vtg, cosb, sinb);

    // attention: 512 blocks (8 bg x 4 heads x 16 pair-groups), 33 tiles/wave
    attn_kernel<<<dim3(512), blk, 0, stream>>>(qkv, Vtg, maskb);

    // GEMM2: out = attn_out(q-slice of qkv, lda=1536) @ Wot^T  (fp32 out)
    gemm2_bt<<<dim3(H_ / 128, M / 64), blk, 0, stream>>>(qkv, QKVW, Wot, out, H_, H_);
}

// Round 5
// 200.970 us; speedup vs baseline: 1.4381x; 1.4081x over previous
//
#include <hip/hip_runtime.h>
#include <math.h>

#define B_   2
#define S_   2048
#define H_   1024
#define NH_  16
#define NKV_ 4
#define HD_  64
#define R_   (NH_ / NKV_)   // 4 q-heads per kv-head
#define QKVW 1536           // qkv row width (q 0..1023 | k 1024..1279 | v 1280..1535)

typedef __attribute__((ext_vector_type(8))) short bf16x8;
typedef __attribute__((ext_vector_type(4))) float f32x4;

__device__ inline short f2bf(float f) {
    unsigned u = __float_as_uint(f);
    u += 0x7FFF + ((u >> 16) & 1);     // RNE to bf16
    return (short)(u >> 16);
}

// async global->LDS, 16 B per lane; lptr is the wave-uniform chunk base,
// HW scatters lane i's 16 B at lptr + i*16 (m97/m104 semantics).
__device__ inline void gload_lds16(const void* gptr, void* lptr) {
    __builtin_amdgcn_global_load_lds(
        (const __attribute__((address_space(1))) unsigned int*)gptr,
        (__attribute__((address_space(3))) unsigned int*)lptr,
        16, 0, 0);
}

// ---------------------------------------------------------------------------
// All four weight transposes in one launch. 640 blocks of 64x64 tiles.
// ---------------------------------------------------------------------------
__global__ __launch_bounds__(256) void tconv_all(const float* __restrict__ Wq,
                                                 const float* __restrict__ Wk,
                                                 const float* __restrict__ Wv,
                                                 const float* __restrict__ Wo,
                                                 short* __restrict__ Wqkvt,
                                                 short* __restrict__ Wot) {
    __shared__ short T[64][68];
    const int bx = blockIdx.x;
    const float* W; short* Wt; int N, idx;
    if (bx < 256)      { W = Wq; Wt = Wqkvt;                     N = 1024; idx = bx; }
    else if (bx < 320) { W = Wk; Wt = Wqkvt + 1024 * 1024;       N = 256;  idx = bx - 256; }
    else if (bx < 384) { W = Wv; Wt = Wqkvt + 1280 * 1024;       N = 256;  idx = bx - 320; }
    else               { W = Wo; Wt = Wot;                       N = 1024; idx = bx - 384; }
    const int ntiles = N >> 6;
    const int n0 = (idx % ntiles) * 64;
    const int k0 = (idx / ntiles) * 64;

    const int tid = threadIdx.x;
    const int r  = tid >> 4;
    const int c4 = (tid & 15) * 4;
#pragma unroll
    for (int t = 0; t < 4; t++) {
        int row = t * 16 + r;
        float4 v = *(const float4*)&W[(size_t)(k0 + row) * N + n0 + c4];
        T[c4 + 0][row] = f2bf(v.x);
        T[c4 + 1][row] = f2bf(v.y);
        T[c4 + 2][row] = f2bf(v.z);
        T[c4 + 3][row] = f2bf(v.w);
    }
    __syncthreads();
#pragma unroll
    for (int t = 0; t < 4; t++) {
        int row = t * 16 + r;          // n index
        short4 o = *(short4*)&T[row][c4];
        *(short4*)&Wt[(size_t)(n0 + row) * 1024 + k0 + c4] = o;
    }
}

// ---------------------------------------------------------------------------
// Fused GEMM1: qkv = bf16(x) @ Wqkvt^T  (RoPE epilogue for q/k, V transposed
// scatter into Vtg). 64x128 tile, BK=32, 256 threads = 4 waves.
// ---------------------------------------------------------------------------
__global__ __launch_bounds__(256) void gemm1_fused(const float* __restrict__ x,
                                                   const short* __restrict__ Bt,
                                                   short* __restrict__ qkv,
                                                   short* __restrict__ Vtg,
                                                   const float* __restrict__ cosb,
                                                   const float* __restrict__ sinb) {
    __shared__ short Ah[64 * 32];    // [row][k] 4 KB
    __shared__ short Bh[128 * 32];   // [col][k] 8 KB

    const int tid  = threadIdx.x;
    const int w    = tid >> 6;
    const int lane = tid & 63;
    const int ln   = lane & 15;
    const int qd   = lane >> 4;
    const int wr   = w >> 1, wc = w & 1;
    const int row0 = blockIdx.y * 64;
    const int col0 = blockIdx.x * 128;

    const int sr = lane >> 2;        // 0..15
    const int sk = (lane & 3) * 8;   // k element offset
    const int ar  = tid >> 2;        // 0..63  (A convert-stage row)
    const int ac8 = (tid & 3) * 8;   // 0,8,16,24

    f32x4 acc[2][4];
#pragma unroll
    for (int mi = 0; mi < 2; mi++)
#pragma unroll
        for (int ni = 0; ni < 4; ni++)
            acc[mi][ni] = (f32x4){0.f, 0.f, 0.f, 0.f};

    for (int k0 = 0; k0 < 1024; k0 += 32) {
        __syncthreads();   // previous iter's frag reads done
        // A: fp32 -> bf16 in registers -> LDS
        {
            const float* xp = x + (size_t)(row0 + ar) * H_ + k0 + ac8;
            float4 a = *(const float4*)xp;
            float4 b2 = *(const float4*)(xp + 4);
            bf16x8 o;
            o[0] = f2bf(a.x);  o[1] = f2bf(a.y);  o[2] = f2bf(a.z);  o[3] = f2bf(a.w);
            o[4] = f2bf(b2.x); o[5] = f2bf(b2.y); o[6] = f2bf(b2.z); o[7] = f2bf(b2.w);
            *(bf16x8*)&Ah[ar * 32 + ac8] = o;
        }
        // B: bf16 glds (wave w stages cols w*32..w*32+31)
        gload_lds16(Bt + (size_t)(col0 + w * 32 + sr) * 1024 + k0 + sk, &Bh[(w * 32) * 32]);
        gload_lds16(Bt + (size_t)(col0 + w * 32 + 16 + sr) * 1024 + k0 + sk, &Bh[(w * 32 + 16) * 32]);
        __syncthreads();

        bf16x8 af[2], bfr[4];
#pragma unroll
        for (int mi = 0; mi < 2; mi++)
            af[mi] = *(const bf16x8*)&Ah[(wr * 32 + mi * 16 + ln) * 32 + qd * 8];
#pragma unroll
        for (int ni = 0; ni < 4; ni++)
            bfr[ni] = *(const bf16x8*)&Bh[(wc * 64 + ni * 16 + ln) * 32 + qd * 8];
#pragma unroll
        for (int mi = 0; mi < 2; mi++)
#pragma unroll
            for (int ni = 0; ni < 4; ni++)
                acc[mi][ni] = __builtin_amdgcn_mfma_f32_16x16x32_bf16(af[mi], bfr[ni], acc[mi][ni], 0, 0, 0);
    }

    const int colw = col0 + wc * 64;          // this wave's 64-col half
    if (colw < H_ + NKV_ * HD_) {
        // ---- q or k columns: RoPE in fp32, store bf16 to qkv ----
#pragma unroll
        for (int mi = 0; mi < 2; mi++)
#pragma unroll
            for (int i = 0; i < 4; i++) {
                const int row  = row0 + wr * 32 + mi * 16 + qd * 4 + i;
                const int spos = row & (S_ - 1);
                const float* cp = cosb + (size_t)spos * HD_;
                const float* sp = sinb + (size_t)spos * HD_;
                float o0[4];
#pragma unroll
                for (int ni = 0; ni < 2; ni++) {
                    const int d = ni * 16 + ln;
                    float x0 = acc[mi][ni][i], x1 = acc[mi][ni + 2][i];
                    o0[ni]     = x0 * cp[d]      - x1 * sp[d];
                    o0[ni + 2] = x1 * cp[d + 32] + x0 * sp[d + 32];
                }
                short* Cp = qkv + (size_t)row * QKVW + colw + ln;
#pragma unroll
                for (int ni = 0; ni < 4; ni++) Cp[ni * 16] = f2bf(o0[ni]);
            }
    } else {
        // ---- v columns: transposed scatter into Vtg[(b*NKV+g)*HD+d][s] ----
        const int g = (colw - (H_ + NKV_ * HD_)) >> 6;
#pragma unroll
        for (int mi = 0; mi < 2; mi++) {
            const int rbase = row0 + wr * 32 + mi * 16 + qd * 4;   // i = +0..3
            const int bg = ((rbase >> 11) * NKV_) + g;
            const int s0 = rbase & (S_ - 1);
#pragma unroll
            for (int ni = 0; ni < 4; ni++) {
                const int d = ni * 16 + ln;
                short4 pk = { f2bf(acc[mi][ni][0]), f2bf(acc[mi][ni][1]),
                              f2bf(acc[mi][ni][2]), f2bf(acc[mi][ni][3]) };
                *(short4*)&Vtg[((size_t)bg * HD_ + d) * S_ + s0] = pk;
            }
        }
    }
}

// ---------------------------------------------------------------------------
// bf16 MFMA GEMM, B^T form: C[M,N] = A[M,K] @ Bt[N,K]^T (fp32 out).
// 64x128 tile, BK=32, 256 threads. Used for the output projection.
// ---------------------------------------------------------------------------
__global__ __launch_bounds__(256) void gemm2_bt(const short* __restrict__ A, int lda,
                                                const short* __restrict__ Bt,
                                                float* __restrict__ C, int ldc,
                                                int K) {
    __shared__ short Ah[64 * 32];
    __shared__ short Bh[128 * 32];

    const int tid  = threadIdx.x;
    const int w    = tid >> 6;
    const int lane = tid & 63;
    const int ln   = lane & 15;
    const int qd   = lane >> 4;
    const int wr   = w >> 1, wc = w & 1;
    const int row0 = blockIdx.y * 64;
    const int col0 = blockIdx.x * 128;

    const int sr = lane >> 2;
    const int sk = (lane & 3) * 8;

    f32x4 acc[2][4];
#pragma unroll
    for (int mi = 0; mi < 2; mi++)
#pragma unroll
        for (int ni = 0; ni < 4; ni++)
            acc[mi][ni] = (f32x4){0.f, 0.f, 0.f, 0.f};

    for (int k0 = 0; k0 < K; k0 += 32) {
        __syncthreads();
        gload_lds16(A + (size_t)(row0 + w * 16 + sr) * lda + k0 + sk, &Ah[(w * 16) * 32]);
        gload_lds16(Bt + (size_t)(col0 + w * 32 + sr) * K + k0 + sk, &Bh[(w * 32) * 32]);
        gload_lds16(Bt + (size_t)(col0 + w * 32 + 16 + sr) * K + k0 + sk, &Bh[(w * 32 + 16) * 32]);
        __syncthreads();

        bf16x8 af[2], bfr[4];
#pragma unroll
        for (int mi = 0; mi < 2; mi++)
            af[mi] = *(const bf16x8*)&Ah[(wr * 32 + mi * 16 + ln) * 32 + qd * 8];
#pragma unroll
        for (int ni = 0; ni < 4; ni++)
            bfr[ni] = *(const bf16x8*)&Bh[(wc * 64 + ni * 16 + ln) * 32 + qd * 8];
#pragma unroll
        for (int mi = 0; mi < 2; mi++)
#pragma unroll
            for (int ni = 0; ni < 4; ni++)
                acc[mi][ni] = __builtin_amdgcn_mfma_f32_16x16x32_bf16(af[mi], bfr[ni], acc[mi][ni], 0, 0, 0);
    }

#pragma unroll
    for (int mi = 0; mi < 2; mi++)
#pragma unroll
        for (int i = 0; i < 4; i++) {
            const size_t row = row0 + wr * 32 + mi * 16 + qd * 4 + i;
            float* Cp = C + row * ldc + col0 + wc * 64 + ln;
#pragma unroll
            for (int ni = 0; ni < 4; ni++) Cp[ni * 16] = acc[mi][ni][i];
        }
}

// ---------------------------------------------------------------------------
// bf16 MFMA flash attention v15: LDS-staged K/V shared by 8 waves,
// uniform pair-blocks.
//   Evidence base: attn is bound by 64-B L2 line-request rate
//   (v12: 8.9M lines/77us = 116 G/s; v14: 17.3M/154us = 112 G/s — same
//   ceiling, time scales with line count). Fix: fetch each K/V tile ONCE
//   per block (coalesced stage into LDS), share across 8 waves.
//   - 256 blocks x 512 threads. Block = (b,g,h, pair a): waves 0-3 = strips
//     of q-tile a, waves 4-7 = strips of q-tile 15-a. Per-block compute =
//     132 wave-tiles for EVERY a (uniform). Staged tiles = 32-2a.
//   - v11-proven staging: reg-prefetch tile kt+1 during compute of kt,
//     write to LDS buf^1, ONE barrier per tile. Prefetch latency drains
//     during ~1400cy compute -> no exposed vmcnt at barrier.
//   - Waves past their diagonal (kt > ktd) skip compute, keep staging.
//   - Ps = 16 rows/wave (softmax->write->PV per rg) -> LDS total 55,808 B.
//   - Line requests: 256 x (32-2a avg 25) x 256 lines = 1.6M (5x under v12).
// ---------------------------------------------------------------------------
__global__ __launch_bounds__(512, 2) void attn_kernel(short* __restrict__ qkv,
                                                      const short* __restrict__ Vtg,
                                                      const float* __restrict__ maskb) {
    const int tid  = threadIdx.x;
    const int w    = tid >> 6;           // 0..7
    const int lane = tid & 63;
    const int ln   = lane & 15;
    const int qd   = lane >> 4;

    // fid&7 = bg -> XCD affinity for the K/V slice
    const int fid = blockIdx.x;          // 0..255
    const int bg  = fid & 7;             // b*NKV+g
    const int u   = fid >> 3;            // 0..31
    const int b   = bg >> 2;
    const int g   = bg & 3;
    const int h   = g * R_ + (u & 3);
    const int a   = u >> 2;              // pair index 0..7

    const int qt   = (w < 4) ? a : (15 - a);
    const int st   = w & 3;              // strip within q-tile
    const int rowb = qt * 128 + st * 32; // wave's first q-row
    const int ktd  = 2 * qt + (st >> 1); // wave's diagonal (last) tile
    const int nt   = 32 - 2 * a;         // tiles staged by this block

    __shared__ short Ks[2][64 * 72];     // K  [key][dim], stride 72
    __shared__ short Vt[2][64 * 72];     // V^T [dim][key]
    __shared__ short Ps[8][16 * 72];     // per-wave P round-trip (one rg)
    __shared__ float mskS[2][64];
    short* const ps = Ps[w];

    const short* const Kb = qkv + (size_t)b * S_ * QKVW + H_ + g * HD_;
    const short* const Vb = Vtg + (size_t)bg * HD_ * S_;
    const float* const mb = maskb + b * S_;

    const int fr = tid >> 3;             // 0..63 (staging row)
    const int fc = (tid & 7) * 8;        // staging col (elements)

    // ---- Q B-frags: rows rowb+rg*16+ln ----
    bf16x8 qf[2][2];
#pragma unroll
    for (int rg = 0; rg < 2; rg++) {
        const short* qp = qkv + (size_t)(b * S_ + rowb + rg * 16 + ln) * QKVW + h * HD_;
        qf[rg][0] = *(const bf16x8*)&qp[qd * 8];
        qf[rg][1] = *(const bf16x8*)&qp[32 + qd * 8];
    }

    f32x4 O[2][4] = {};
    float mrow[2] = {-1e30f, -1e30f};
    float lrow[2] = {0.0f, 0.0f};

    // ---- stage tile 0 (coalesced: 8 threads x 16 B per row) ----
    *(bf16x8*)&Ks[0][fr * 72 + fc] = *(const bf16x8*)&Kb[(size_t)fr * QKVW + fc];
    *(bf16x8*)&Vt[0][fr * 72 + fc] = *(const bf16x8*)&Vb[(size_t)fr * S_ + fc];
    if (tid < 64) mskS[0][tid] = mb[tid];
    __syncthreads();

    int cur = 0;
    for (int kt = 0; kt < nt; kt++) {
        const int base = kt * 64;
        const bool pf = (kt + 1 < nt);

        // ---- prefetch tile kt+1 into registers (no wait) ----
        bf16x8 pk, pv;
        float pm = 0.0f;
        if (pf) {
            const int nb = base + 64;
            pk = *(const bf16x8*)&Kb[(size_t)(nb + fr) * QKVW + fc];
            pv = *(const bf16x8*)&Vb[(size_t)fr * S_ + nb + fc];
            if (tid < 64) pm = mb[nb + tid];
        }

        if (kt <= ktd) {   // wave-uniform: tile has unmasked keys for this wave
            // ---- QK^T swapped: St[rg][kg] = S^T tile ----
            f32x4 St[2][4];
#pragma unroll
            for (int kg = 0; kg < 4; kg++) {
                bf16x8 ka0 = *(const bf16x8*)&Ks[cur][(kg * 16 + ln) * 72 + qd * 8];
                bf16x8 ka1 = *(const bf16x8*)&Ks[cur][(kg * 16 + ln) * 72 + 32 + qd * 8];
#pragma unroll
                for (int rg = 0; rg < 2; rg++) {
                    f32x4 z = {0.f, 0.f, 0.f, 0.f};
                    z = __builtin_amdgcn_mfma_f32_16x16x32_bf16(ka0, qf[rg][0], z, 0, 0, 0);
                    St[rg][kg] = __builtin_amdgcn_mfma_f32_16x16x32_bf16(ka1, qf[rg][1], z, 0, 0, 0);
                }
            }

            // ---- V B-frags from LDS (shared across rgs) ----
            bf16x8 vb[2][4];
#pragma unroll
            for (int kc2 = 0; kc2 < 2; kc2++)
#pragma unroll
                for (int dt = 0; dt < 4; dt++)
                    vb[kc2][dt] = *(const bf16x8*)&Vt[cur][(dt * 16 + ln) * 72 + kc2 * 32 + qd * 8];

            // ---- per-lane mask bias for keys base+kg*16+qd*4+i ----
            float mt[4][4];
#pragma unroll
            for (int kg = 0; kg < 4; kg++) {
                float4 mv = *(const float4*)&mskS[cur][kg * 16 + qd * 4];
                mt[kg][0] = (1.0f - mv.x) * -1e9f;
                mt[kg][1] = (1.0f - mv.y) * -1e9f;
                mt[kg][2] = (1.0f - mv.z) * -1e9f;
                mt[kg][3] = (1.0f - mv.w) * -1e9f;
            }

            const bool diag = (kt == ktd);

            // ---- per rg: softmax -> P write -> PV ----
#pragma unroll
            for (int rg = 0; rg < 2; rg++) {
                const int qrow = rowb + rg * 16 + ln;
                float sc[4][4];
#pragma unroll
                for (int kg = 0; kg < 4; kg++) {
                    const int keyb = base + kg * 16 + qd * 4;
#pragma unroll
                    for (int i = 0; i < 4; i++) {
                        float v = fmaf(St[rg][kg][i], 0.125f, mt[kg][i]);
                        sc[kg][i] = (diag && (keyb + i > qrow)) ? -1e30f : v;
                    }
                }
                float mx = sc[0][0];
#pragma unroll
                for (int kg = 0; kg < 4; kg++)
#pragma unroll
                    for (int i = 0; i < 4; i++) mx = fmaxf(mx, sc[kg][i]);
                mx = fmaxf(mx, __shfl_xor(mx, 16));
                mx = fmaxf(mx, __shfl_xor(mx, 32));

                // defer-max (T13): rescale only when some row moved > 8
                if (__ballot(mx > mrow[rg] + 8.0f)) {
                    float nm    = fmaxf(mrow[rg], mx);
                    float alpha = __expf(mrow[rg] - nm);
                    lrow[rg] *= alpha;
#pragma unroll
                    for (int i = 0; i < 4; i++) {
                        float av = __shfl(alpha, qd * 4 + i);
#pragma unroll
                        for (int dt = 0; dt < 4; dt++) O[rg][dt][i] *= av;
                    }
                    mrow[rg] = nm;
                }
                const float nm = mrow[rg];

                float ls = 0.0f;
#pragma unroll
                for (int kg = 0; kg < 4; kg++)
#pragma unroll
                    for (int i = 0; i < 4; i++) {
                        float p = __expf(sc[kg][i] - nm);
                        sc[kg][i] = p;
                        ls += p;
                    }
                ls += __shfl_xor(ls, 16);
                ls += __shfl_xor(ls, 32);
                lrow[rg] += ls;

#pragma unroll
                for (int kg = 0; kg < 4; kg++) {
                    short4 pk2 = { f2bf(sc[kg][0]), f2bf(sc[kg][1]),
                                   f2bf(sc[kg][2]), f2bf(sc[kg][3]) };
                    *(short4*)&ps[ln * 72 + kg * 16 + qd * 4] = pk2;
                }

                // PV: O[rg] += P[rg] @ V (same-wave LDS write->read, in order)
#pragma unroll
                for (int kc2 = 0; kc2 < 2; kc2++) {
                    bf16x8 pa = *(const bf16x8*)&ps[ln * 72 + kc2 * 32 + qd * 8];
#pragma unroll
                    for (int dt = 0; dt < 4; dt++)
                        O[rg][dt] = __builtin_amdgcn_mfma_f32_16x16x32_bf16(pa, vb[kc2][dt], O[rg][dt], 0, 0, 0);
                }
            }
        }

        // ---- write prefetched tile into the other buffer ----
        if (pf) {
            const int nxt = cur ^ 1;
            *(bf16x8*)&Ks[nxt][fr * 72 + fc] = pk;
            *(bf16x8*)&Vt[nxt][fr * 72 + fc] = pv;
            if (tid < 64) mskS[nxt][tid] = pm;
        }
        __syncthreads();
        cur ^= 1;
    }

    // ---- finalize: l replicated over qd; write bf16 into q-slice ----
#pragma unroll
    for (int rg = 0; rg < 2; rg++)
#pragma unroll
        for (int i = 0; i < 4; i++) {
            float li  = __shfl(lrow[rg], qd * 4 + i);
            float inv = 1.0f / li;
            const int row = rowb + rg * 16 + qd * 4 + i;
            short* op = qkv + (size_t)(b * S_ + row) * QKVW + h * HD_ + ln;
#pragma unroll
            for (int dt = 0; dt < 4; dt++) op[dt * 16] = f2bf(O[rg][dt][i] * inv);
        }
}

// ---------------------------------------------------------------------------
extern "C" void kernel_launch(void* const* d_in, const int* in_sizes, int n_in,
                              void* d_out, int out_size, void* d_ws, size_t ws_size,
                              hipStream_t stream) {
    const float* x     = (const float*)d_in[0];
    const float* cosb  = (const float*)d_in[1];
    const float* sinb  = (const float*)d_in[2];
    const float* maskb = (const float*)d_in[3];
    const float* Wq    = (const float*)d_in[4];
    const float* Wk    = (const float*)d_in[5];
    const float* Wv    = (const float*)d_in[6];
    const float* Wo    = (const float*)d_in[7];

    const int M = B_ * S_;   // 4096

    // ws: qkv | Wqkvt | Wot | Vtg  (19.9 MB bf16). d_out used only for out.
    short* qkv   = (short*)d_ws;                     // [4096][1536]
    short* Wqkvt = qkv + (size_t)M * QKVW;           // [1536][1024]
    short* Wot   = Wqkvt + (size_t)QKVW * H_;        // [1024][1024]
    short* Vtg   = Wot + (size_t)H_ * H_;            // [8*64][2048]
    float* out   = (float*)d_out;

    dim3 blk(256);

    tconv_all<<<dim3(640), blk, 0, stream>>>(Wq, Wk, Wv, Wo, Wqkvt, Wot);

    // GEMM1 fused: qkv(q,k roped) + Vtg, straight from fp32 x
    gemm1_fused<<<dim3(QKVW / 128, M / 64), blk, 0, stream>>>(x, Wqkvt, qkv, Vtg, cosb, sinb);

    // attention: 256 pair-blocks x 512 threads (8 waves), uniform 132
    // wave-tiles/block, K/V staged once per block
    attn_kernel<<<dim3(256), dim3(512), 0, stream>>>(qkv, Vtg, maskb);

    // GEMM2: out = attn_out(q-slice of qkv, lda=1536) @ Wot^T  (fp32 out)
    gemm2_bt<<<dim3(H_ / 128, M / 64), blk, 0, stream>>>(qkv, QKVW, Wot, out, H_, H_);
}